// Round 10
// baseline (129.122 us; speedup 1.0000x reference)
//
#include <hip/hip_runtime.h>
#include <stdint.h>

// LocalConnectivity: out[i][j] = sum_{1<=|dx|+|dy|<=5} w_{|dx|+|dy|} * s[(i+dx)&4095][(j+dy)&4095]
// Separable: out[i][j] = sum_{dx=-5..5} r^|dx| * H_{5-|dx|}[i+dx][j] - s[i][j],
//   H_k[t][j] = sum_{|dy|<=k} r^|dy| s[t][j+dy]
//
// Plateau analysis (R12-R16): three structurally different kernels all stall
// at 52-57us with nothing saturated (VALU<=22%, HBM<=36%, L2 ~12%). Common
// factor since R8: NONTEMPORAL stores. Write rate across all NT kernels is
// pinned at 1.2-1.5 TB/s (65.5MB exact, zero churn => NT bypasses L2/L3 and
// drains through a shallow per-CU path to HBM). R7 (regular stores) was the
// only kernel to sustain 3.8 TB/s. R15's depth-4 register pipeline was
// collapsed by the compiler (VGPR 84 proves buffers weren't kept) -> source-
// level register pipelining is dead on this compiler.
// R17: single-variable ablation. R13 structure VERBATIM (LDS-staged 1024x8
// tile, measured best 43.5us), only change: NT stores -> regular stores
// (write-allocate in L2, lazy write-back). If NT was the floor: ~28-34us.

#define GMASK  4095
#define TR     8               // output rows per block
#define NRW    (TR + 10)       // 18 staged input rows
#define LW     1040            // LDS row: 8 pad | 1024 | 8 pad  (floats)

typedef float f4 __attribute__((ext_vector_type(4), aligned(16)));

#define GLOBAL_AS __attribute__((address_space(1)))
#define LDS_AS    __attribute__((address_space(3)))

__device__ __forceinline__ void stage16(const float* g, float* l) {
    // wave-collective: lane i loads 16B from (g + i*4 floats) into l + i*16B
    __builtin_amdgcn_global_load_lds((const GLOBAL_AS uint32_t*)g,
                                     (LDS_AS uint32_t*)l, 16, 0, 0);
}

__device__ __forceinline__ float uniform_f(float x) {
    union { float f; int i; } u;
    u.f = x;
    u.i = __builtin_amdgcn_readfirstlane(u.i);
    return u.f;
}

__global__ __launch_bounds__(256)
void diamond_stencil(const float* __restrict__ s, const float* __restrict__ w,
                     float* __restrict__ out)
{
    __shared__ float tile[NRW][LW];          // 18*1040*4 = 74880 B

    const int tid  = threadIdx.x;
    const int lane = tid & 63;
    const int wv   = tid >> 6;               // wave 0..3

    // XCD band swizzle: 2048 blocks, xcd k owns y-chunks [k*64,(k+1)*64),
    // strips fastest -> halo-sharing neighbors co-resident in one L2.
    const int bid = blockIdx.x;              // 0..2047
    const int xcd = bid & 7;
    const int idx = bid >> 3;                // 0..255
    const int bx  = idx & 3;                 // column strip (1024 cols)
    const int by  = xcd * 64 + (idx >> 2);   // y-chunk 0..511

    const int j0 = bx << 10;                 // strip base col (multiple of 1024)
    const int t0 = by * TR;                  // first output row

    // ---- async stage: main 1024 floats/row; wave wv does rows wv, wv+4, ... ----
    for (int r = wv; r < NRW; r += 4) {
        const float* srow = s + ((size_t)((t0 - 5 + r) & GMASK) << 12);
        float* lrow = &tile[r][8];
#pragma unroll
        for (int q = 0; q < 4; ++q)          // 4 x (64 lanes x 16B) = 4 KB row
            stage16(srow + j0 + q * 256 + lane * 4, lrow + q * 256);
    }

    // ---- halo: 18 rows x {8 left, 8 right} floats = 72 x 16B chunks ----
    if (tid < NRW * 4) {
        const int r  = tid >> 2, p = tid & 3;
        const int gc = (p < 2 ? j0 - 8 + p * 4 : j0 + 1024 + (p - 2) * 4) & GMASK;
        const int lc = (p < 2 ? p * 4 : 1032 + (p - 2) * 4);
        const float* srow = s + ((size_t)((t0 - 5 + r) & GMASK) << 12);
        *(f4*)&tile[r][lc] = *(const f4*)(srow + gc);   // 16B aligned both sides
    }

    __syncthreads();   // drains vmcnt (global_load_lds) + lgkm (halo ds_write)

    float wgt[6];
    wgt[0] = 1.0f;
#pragma unroll
    for (int d = 1; d <= 5; ++d) wgt[d] = uniform_f(w[d - 1]);   // exp(-d/2)

    float acc[TR][4];
#pragma unroll
    for (int a = 0; a < TR; ++a)
#pragma unroll
        for (int c = 0; c < 4; ++c) acc[a][c] = 0.0f;

    const int tc = tid * 4;                  // this thread's padded col base

#pragma unroll
    for (int r = 0; r < NRW; ++r) {
        // aligned 20-float window: padded cols tc .. tc+19 (need tc+3 .. tc+16)
        const f4* lp = (const f4*)&tile[r][tc];   // (r*1040 + tc)*4 is 16B-aligned
        const f4 A = lp[0], B = lp[1], C = lp[2], D = lp[3], E = lp[4];
        float f[20];
        f[0]=A.x; f[1]=A.y; f[2]=A.z; f[3]=A.w;
        f[4]=B.x; f[5]=B.y; f[6]=B.z; f[7]=B.w;
        f[8]=C.x; f[9]=C.y; f[10]=C.z; f[11]=C.w;
        f[12]=D.x; f[13]=D.y; f[14]=D.z; f[15]=D.w;
        f[16]=E.x; f[17]=E.y; f[18]=E.z; f[19]=E.w;

#pragma unroll
        for (int c = 0; c < 4; ++c) {
            const float ctr = f[8 + c];      // padded col tc+8+c = real col tc+c
            float Hs[6];
            Hs[0] = ctr;
#pragma unroll
            for (int k = 1; k <= 5; ++k)
                Hs[k] = Hs[k - 1] + wgt[k] * (f[8 + c - k] + f[8 + c + k]);

            // input row t = t0-5+r feeds output row o = t0+a iff |r-5-a| <= 5
#pragma unroll
            for (int a = 0; a < TR; ++a) {
                const int d = r - 5 - a;     // compile-time
                if (d < -5 || d > 5) continue;
                if (d == 0)
                    acc[a][c] += Hs[5] - ctr;          // center excluded
                else {
                    const int ad = d < 0 ? -d : d;
                    acc[a][c] += wgt[ad] * Hs[5 - ad];
                }
            }
        }
    }

    // store 8 rows x 4 cols — REGULAR stores (R17 ablation: NT was the suspect
    // floor; let L2 write-allocate and drain lazily)
#pragma unroll
    for (int a = 0; a < TR; ++a) {
        float* op = out + ((size_t)(t0 + a) << 12) + j0 + tc;
        f4 r0;
        r0.x = acc[a][0]; r0.y = acc[a][1]; r0.z = acc[a][2]; r0.w = acc[a][3];
        *(f4*)op = r0;
    }
}

extern "C" void kernel_launch(void* const* d_in, const int* in_sizes, int n_in,
                              void* d_out, int out_size, void* d_ws, size_t ws_size,
                              hipStream_t stream)
{
    const float* s = (const float*)d_in[0];   // grid_spikes [4096*4096] f32
    const float* w = (const float*)d_in[1];   // distance_weights [5] f32
    float* out = (float*)d_out;               // [4096*4096] f32

    // 2048 blocks = 4 col strips x 512 row-chunks, XCD-band swizzled in-kernel
    dim3 grid(2048);
    dim3 block(256);
    diamond_stencil<<<grid, block, 0, stream>>>(s, w, out);
}

// Round 13
// 125.251 us; speedup vs baseline: 1.0309x; 1.0309x over previous
//
#include <hip/hip_runtime.h>
#include <stdint.h>

// LocalConnectivity: out[i][j] = sum_{1<=|dx|+|dy|<=5} w_{|dx|+|dy|} * s[(i+dx)&4095][(j+dy)&4095]
// Separable: out[i][j] = sum_{dx=-5..5} r^|dx| * H_{5-|dx|}[i+dx][j] - s[i][j],
//   H_k[t][j] = sum_{|dy|<=k} r^|dy| s[t][j+dy]
//
// R13/R17 accounting: VALU 17-24k cy, LDS port 34.6k cy, observed 104k cy/CU
// -> ~65% idle = block-start vmcnt(0) drains + 2.25x staging amplification.
// R18/R19 (persistent ring, 130KiB LDS): "container failed twice" x2. Only
// novel risk factor was 130KiB static LDS (never ran >75KiB here). R20:
// same structure scaled to 66KiB: 512-col strip, 128 thr (2 waves), RING=32
// x LW=528 -> 67584B -> 2 blocks/CU (two independent pipelines per CU).
// Block owns 512 cols x 64 rows, walks 8 tiles of 8 rows. Tile t+1 reuses
// 10 of 18 staged rows -> stage 8 new rows/iter (amp 1.16x). stage(t+1)
// issued BEFORE compute(t) -> barrier drain ~free. Ring: 26-row live window
// < 32 slots => disjoint, race-free with plain __syncthreads.

#define GMASK  4095
#define TR     8               // output rows per tile
#define NTILE  8               // tiles per block (64 rows)
#define RING   32              // LDS row slots (power of 2)
#define SW     512             // strip width (cols per block)
#define LW     (SW + 16)       // 8 pad | 512 | 8 pad = 528 floats per row

typedef float f4 __attribute__((ext_vector_type(4), aligned(16)));

#define GLOBAL_AS __attribute__((address_space(1)))
#define LDS_AS    __attribute__((address_space(3)))

__device__ __forceinline__ void stage16(const float* g, float* l) {
    // wave-collective: lane i loads 16B from (g + i*4 floats) into l + i*16B
    __builtin_amdgcn_global_load_lds((const GLOBAL_AS uint32_t*)g,
                                     (LDS_AS uint32_t*)l, 16, 0, 0);
}

__device__ __forceinline__ float uniform_f(float x) {
    union { float f; int i; } u;
    u.f = x;
    u.i = __builtin_amdgcn_readfirstlane(u.i);
    return u.f;
}

__global__ __launch_bounds__(128)
void diamond_stencil(const float* __restrict__ s, const float* __restrict__ w,
                     float* __restrict__ out)
{
    __shared__ float ring[RING][LW];         // 32*528*4 = 67584 B -> 2 blocks/CU

    const int tid  = threadIdx.x;            // 0..127 (2 waves)
    const int lane = tid & 63;
    const int wv   = tid >> 6;               // wave 0..1

    // 512 blocks = 8 col strips x 64 row bands; XCD k owns 8 contiguous bands,
    // strips fastest -> halo-sharing neighbors co-resident in one L2.
    const int bid   = blockIdx.x;            // 0..511
    const int xcd   = bid & 7;
    const int idx   = bid >> 3;              // 0..63
    const int strip = idx & 7;               // 0..7
    const int band  = xcd * 8 + (idx >> 3);  // 0..63

    const int j0  = strip << 9;              // strip base col
    const int rb  = band << 6;               // first output row of this block
    const int rb5 = rb - 5;                  // global row of stage counter n=0

    float wgt[6];
    wgt[0] = 1.0f;
#pragma unroll
    for (int d = 1; d <= 5; ++d) wgt[d] = uniform_f(w[d - 1]);   // exp(-d/2)

    const int tc = tid * 4;                  // thread's padded col base (16B-aligned)

    // ---------- staging helper (stream rows n0 .. n0+cnt-1) ----------
    auto stage_rows = [&](int n0, int cnt) {
        // main 512 floats/row: wave wv takes rows n0+wv, n0+wv+2, ...
        for (int n = n0 + wv; n < n0 + cnt; n += 2) {
            const float* srow = s + ((size_t)((rb5 + n) & GMASK) << 12);
            float* lrow = &ring[n & (RING - 1)][8];
            stage16(srow + j0 + lane * 4,       lrow);        // 64 x 16B = 256 floats
            stage16(srow + j0 + 256 + lane * 4, lrow + 256);  // next 256 floats
        }
        // halo: cnt rows x {8 left, 8 right} = cnt*4 f4 chunks (cnt<=18 -> <=72 thr)
        if (tid < cnt * 4) {
            const int rr = tid >> 2, p = tid & 3;
            const int n  = n0 + rr;
            const int gc = (p < 2 ? j0 - 8 + p * 4 : j0 + SW + (p - 2) * 4) & GMASK;
            const int lc = (p < 2 ? p * 4 : 8 + SW + (p - 2) * 4);
            const float* srow = s + ((size_t)((rb5 + n) & GMASK) << 12);
            *(f4*)&ring[n & (RING - 1)][lc] = *(const f4*)(srow + gc);
        }
    };

    // ---------- prologue: stream rows 0..17 (tile 0 needs them) ----------
    stage_rows(0, 18);
    __syncthreads();

    for (int t = 0; t < NTILE; ++t) {
        // issue next tile's 8 rows FIRST: they land during compute, so the
        // barrier's vmcnt(0) drain at iter end is ~free.
        if (t < NTILE - 1) stage_rows(18 + 8 * t, 8);

        float acc[TR][4];
#pragma unroll
        for (int a = 0; a < TR; ++a)
#pragma unroll
            for (int c = 0; c < 4; ++c) acc[a][c] = 0.0f;

        const int n0 = 8 * t;                // stream row of k=0
#pragma unroll
        for (int k = 0; k < TR + 10; ++k) {  // 18 input rows
            const int slot = (n0 + k) & (RING - 1);
            const f4* lp = (const f4*)&ring[slot][tc];   // 16B-aligned
            const f4 A = lp[0], B = lp[1], C = lp[2], D = lp[3], E = lp[4];
            float f[20];
            f[0]=A.x;  f[1]=A.y;  f[2]=A.z;  f[3]=A.w;
            f[4]=B.x;  f[5]=B.y;  f[6]=B.z;  f[7]=B.w;
            f[8]=C.x;  f[9]=C.y;  f[10]=C.z; f[11]=C.w;
            f[12]=D.x; f[13]=D.y; f[14]=D.z; f[15]=D.w;
            f[16]=E.x; f[17]=E.y; f[18]=E.z; f[19]=E.w;

#pragma unroll
            for (int c = 0; c < 4; ++c) {
                const float ctr = f[8 + c];  // padded tc+8+c = real col j0+tc+c
                float Hs[6];
                Hs[0] = ctr;
#pragma unroll
                for (int q = 1; q <= 5; ++q)
                    Hs[q] = Hs[q - 1] + wgt[q] * (f[8 + c - q] + f[8 + c + q]);

                // input row k feeds output row a iff |k-5-a| <= 5
#pragma unroll
                for (int a = 0; a < TR; ++a) {
                    const int d = k - 5 - a;           // compile-time
                    if (d < -5 || d > 5) continue;
                    if (d == 0)
                        acc[a][c] += Hs[5] - ctr;      // center excluded
                    else {
                        const int ad = d < 0 ? -d : d;
                        acc[a][c] += wgt[ad] * Hs[5 - ad];
                    }
                }
            }
        }

        // store this tile: 8 rows x 4 cols per thread (regular stores; NT
        // exonerated in R17)
#pragma unroll
        for (int a = 0; a < TR; ++a) {
            float* op = out + ((size_t)(rb + 8 * t + a) << 12) + j0 + tc;
            f4 r0;
            r0.x = acc[a][0]; r0.y = acc[a][1]; r0.z = acc[a][2]; r0.w = acc[a][3];
            *(f4*)op = r0;
        }

        __syncthreads();   // staged rows for t+1 now visible; drain ~free
    }
}

extern "C" void kernel_launch(void* const* d_in, const int* in_sizes, int n_in,
                              void* d_out, int out_size, void* d_ws, size_t ws_size,
                              hipStream_t stream)
{
    const float* s = (const float*)d_in[0];   // grid_spikes [4096*4096] f32
    const float* w = (const float*)d_in[1];   // distance_weights [5] f32
    float* out = (float*)d_out;               // [4096*4096] f32

    // 512 persistent blocks (2/CU): 8 col strips x 64 row bands
    dim3 grid(512);
    dim3 block(128);
    diamond_stencil<<<grid, block, 0, stream>>>(s, w, out);
}